// Round 1
// baseline (289.436 us; speedup 1.0000x reference)
//
#include <hip/hip_runtime.h>
#include <math.h>

#define BATCH 64
#define HH 512
#define WW 512
#define KRAD 15
#define KSZ 31
#define NTOT ((size_t)BATCH * HH * WW)

// ---------------------------------------------------------------------------
// Pass 1: horizontal 31-tap box sum (zero-padded) per row, via register
// prefix sums + wave shuffles. One wave (64 lanes) per 512-wide row,
// 8 columns per lane. 4 rows per 256-thread block. No LDS.
// Also zeroes the 3 double accumulators (safe: pass 2 is stream-ordered after).
// ---------------------------------------------------------------------------
__global__ __launch_bounds__(256) void hbox_kernel(const float* __restrict__ t,
                                                   float* __restrict__ Hbuf,
                                                   double* __restrict__ acc) {
    if (blockIdx.x == 0 && threadIdx.x < 3) acc[threadIdx.x] = 0.0;

    const int g    = blockIdx.x * 4 + (threadIdx.x >> 6);  // global row (b*512+y)
    const int lane = threadIdx.x & 63;

    const float4* rp = (const float4*)(t + (size_t)g * WW);
    float4 a  = rp[2 * lane];
    float4 b4 = rp[2 * lane + 1];
    float v[8] = {a.x, a.y, a.z, a.w, b4.x, b4.y, b4.z, b4.w};

    // local inclusive prefix
    float T = 0.0f;
    float P[8];
#pragma unroll
    for (int j = 0; j < 8; ++j) { T += v[j]; P[j] = T; }

    // wave-inclusive scan of per-thread totals
    float incl = T;
#pragma unroll
    for (int d = 1; d < 64; d <<= 1) {
        float n = __shfl_up(incl, d, 64);
        if (lane >= d) incl += n;
    }
    const float excl = incl - T;
    const float tot  = __shfl(incl, 63, 64);  // full-row sum = P[511]

    // P[j] -> global inclusive prefix at column x = 8*lane + j
#pragma unroll
    for (int j = 0; j < 8; ++j) P[j] += excl;

    float o[8];
#pragma unroll
    for (int j = 0; j < 8; ++j) {
        // hi = P[min(x+15, 511)];  x+15 = 8*(lane + ((j+15)>>3)) + ((j+15)&7)
        const int q   = j + 15;              // 15..22 (compile-time)
        const int seg = lane + (q >> 3);     // lane+1 or lane+2
        float hi_sh = __shfl(P[q & 7], seg > 63 ? 63 : seg, 64);
        float hi    = (seg > 63) ? tot : hi_sh;
        // lo = (x >= 16) ? P[x-16] : 0;  x-16 = 8*(lane-2) + j
        float lo_sh = __shfl(P[j], lane >= 2 ? lane - 2 : 0, 64);
        float lo    = (lane >= 2) ? lo_sh : 0.0f;
        o[j] = hi - lo;
    }

    float4* dp = (float4*)(Hbuf + (size_t)g * WW);
    float4 s0 = {o[0], o[1], o[2], o[3]};
    float4 s1 = {o[4], o[5], o[6], o[7]};
    dp[2 * lane]     = s0;
    dp[2 * lane + 1] = s1;
}

// ---------------------------------------------------------------------------
// Pass 2: vertical 31-tap box (running sum down a column) fused with the
// elementwise loss math and the three global reductions.
// Thread <-> (batch, column, 128-row chunk). Fully coalesced global access.
// ---------------------------------------------------------------------------
#define YCHUNK 128
__global__ __launch_bounds__(256) void fused_kernel(const float* __restrict__ logits,
                                                    const float* __restrict__ targ,
                                                    const float* __restrict__ Hbuf,
                                                    double* __restrict__ acc) {
    const int tid   = blockIdx.x * 256 + threadIdx.x;
    const int x     = tid & (WW - 1);
    const int bc    = tid >> 9;
    const int chunk = bc & 3;           // 512/128 = 4 chunks
    const int b     = bc >> 2;
    const int y0    = chunk * YCHUNK;

    const size_t base = (size_t)b * HH * WW + x;
    const float* Hp = Hbuf   + base;
    const float* Tp = targ   + base;
    const float* Lp = logits + base;

    // warm-up: window sum for rows [y0-15, y0+15] (clipped low; high side <512)
    float vsum = 0.0f;
    {
        int lo = y0 - KRAD; if (lo < 0) lo = 0;
        const int hi = y0 + KRAD;
        for (int k = lo; k <= hi; ++k) vsum += Hp[(size_t)k * WW];
    }

    const float inv_ksq = 1.0f / (float)(KSZ * KSZ);
    float a_wbce = 0.0f, a_int = 0.0f, a_tot = 0.0f;

    for (int y = y0; y < y0 + YCHUNK; ++y) {
        const float s = vsum * inv_ksq;
        const float t = Tp[(size_t)y * WW];
        const float L = Lp[(size_t)y * WW];

        const float weit = 1.0f + 5.0f * fabsf(s - t);
        // bce = softplus(L) - t*L   (== -[t log p + (1-t) log(1-p)])
        const float sp  = fmaxf(L, 0.0f) + log1pf(__expf(-fabsf(L)));
        const float bce = sp - t * L;
        const float p   = 1.0f / (1.0f + __expf(-L));

        a_wbce += weit * bce;
        a_int  += p * t * weit;
        a_tot  += (p + t) * weit;

        // slide window: [y-15, y+15] -> [y-14, y+16]
        const int add = y + KRAD + 1;
        const int sub = y - KRAD;
        if (add <= HH - 1) vsum += Hp[(size_t)add * WW];
        if (sub >= 0)      vsum -= Hp[(size_t)sub * WW];
    }

    // wave reduce (64 lanes)
#pragma unroll
    for (int off = 32; off > 0; off >>= 1) {
        a_wbce += __shfl_down(a_wbce, off, 64);
        a_int  += __shfl_down(a_int,  off, 64);
        a_tot  += __shfl_down(a_tot,  off, 64);
    }

    __shared__ float red[3][4];
    const int wave = threadIdx.x >> 6;
    if ((threadIdx.x & 63) == 0) {
        red[0][wave] = a_wbce; red[1][wave] = a_int; red[2][wave] = a_tot;
    }
    __syncthreads();
    if (threadIdx.x == 0) {
        double w = 0.0, i2 = 0.0, t2 = 0.0;
        for (int k = 0; k < 4; ++k) { w += red[0][k]; i2 += red[1][k]; t2 += red[2][k]; }
        atomicAdd(&acc[0], w);
        atomicAdd(&acc[1], i2);
        atomicAdd(&acc[2], t2);
    }
}

// ---------------------------------------------------------------------------
// Pass 3: finalize the scalar.
// ---------------------------------------------------------------------------
__global__ void finalize_kernel(const double* __restrict__ acc, float* __restrict__ out) {
    if (threadIdx.x == 0 && blockIdx.x == 0) {
        const double wbce  = acc[0] / (double)NTOT;
        const double inter = acc[1];
        const double total = acc[2];
        const double union_ = total - inter;
        const double wiou  = 1.0 - (inter + 1.0) / (union_ + 1.0);
        out[0] = (float)(wbce + wiou);
    }
}

extern "C" void kernel_launch(void* const* d_in, const int* in_sizes, int n_in,
                              void* d_out, int out_size, void* d_ws, size_t ws_size,
                              hipStream_t stream) {
    const float* logits = (const float*)d_in[0];
    const float* targ   = (const float*)d_in[1];
    float* out          = (float*)d_out;

    double* acc  = (double*)d_ws;                       // 3 doubles @ offset 0
    float*  Hbuf = (float*)((char*)d_ws + 256);         // 64 MiB intermediate

    // Pass 1: horizontal box sums (also zeroes acc)
    hbox_kernel<<<BATCH * HH / 4, 256, 0, stream>>>(targ, Hbuf, acc);
    // Pass 2: vertical box + fused loss + reductions
    fused_kernel<<<(BATCH * 4 * WW) / 256, 256, 0, stream>>>(logits, targ, Hbuf, acc);
    // Pass 3: scalar finalize
    finalize_kernel<<<1, 64, 0, stream>>>(acc, out);
}

// Round 2
// 249.121 us; speedup vs baseline: 1.1618x; 1.1618x over previous
//
#include <hip/hip_runtime.h>
#include <math.h>

#define BATCH 64
#define HH 512
#define WW 512
#define KRAD 15
#define KSZ 31
#define NTOT ((size_t)BATCH * HH * WW)

// ---------------------------------------------------------------------------
// Pass 1: horizontal 31-tap box sum (zero-padded) per row, via register
// prefix sums + wave shuffles. One wave (64 lanes) per 512-wide row,
// 8 columns per lane. 4 rows per 256-thread block. No LDS.
// Also zeroes the 3 double accumulators (safe: pass 2 is stream-ordered after).
// ---------------------------------------------------------------------------
__global__ __launch_bounds__(256) void hbox_kernel(const float* __restrict__ t,
                                                   float* __restrict__ Hbuf,
                                                   double* __restrict__ acc) {
    if (blockIdx.x == 0 && threadIdx.x < 3) acc[threadIdx.x] = 0.0;

    const int g    = blockIdx.x * 4 + (threadIdx.x >> 6);  // global row (b*512+y)
    const int lane = threadIdx.x & 63;

    const float4* rp = (const float4*)(t + (size_t)g * WW);
    float4 a  = rp[2 * lane];
    float4 b4 = rp[2 * lane + 1];
    float v[8] = {a.x, a.y, a.z, a.w, b4.x, b4.y, b4.z, b4.w};

    // local inclusive prefix
    float T = 0.0f;
    float P[8];
#pragma unroll
    for (int j = 0; j < 8; ++j) { T += v[j]; P[j] = T; }

    // wave-inclusive scan of per-thread totals
    float incl = T;
#pragma unroll
    for (int d = 1; d < 64; d <<= 1) {
        float n = __shfl_up(incl, d, 64);
        if (lane >= d) incl += n;
    }
    const float excl = incl - T;
    const float tot  = __shfl(incl, 63, 64);  // full-row sum = P[511]

    // P[j] -> global inclusive prefix at column x = 8*lane + j
#pragma unroll
    for (int j = 0; j < 8; ++j) P[j] += excl;

    float o[8];
#pragma unroll
    for (int j = 0; j < 8; ++j) {
        // hi = P[min(x+15, 511)];  x+15 = 8*(lane + ((j+15)>>3)) + ((j+15)&7)
        const int q   = j + 15;              // 15..22 (compile-time)
        const int seg = lane + (q >> 3);     // lane+1 or lane+2
        float hi_sh = __shfl(P[q & 7], seg > 63 ? 63 : seg, 64);
        float hi    = (seg > 63) ? tot : hi_sh;
        // lo = (x >= 16) ? P[x-16] : 0;  x-16 = 8*(lane-2) + j
        float lo_sh = __shfl(P[j], lane >= 2 ? lane - 2 : 0, 64);
        float lo    = (lane >= 2) ? lo_sh : 0.0f;
        o[j] = hi - lo;
    }

    float4* dp = (float4*)(Hbuf + (size_t)g * WW);
    float4 s0 = {o[0], o[1], o[2], o[3]};
    float4 s1 = {o[4], o[5], o[6], o[7]};
    dp[2 * lane]     = s0;
    dp[2 * lane + 1] = s1;
}

// ---------------------------------------------------------------------------
// Pass 2: vertical 31-tap box (running sum down a column) fused with the
// elementwise loss math and the three global reductions.
// Thread <-> (batch, column, 32-row chunk): 2048 blocks -> 32 waves/CU.
// Cheap math: one v_exp + one v_log + one v_rcp per element.
// ---------------------------------------------------------------------------
#define YCHUNK 32
__global__ __launch_bounds__(256, 8) void fused_kernel(const float* __restrict__ logits,
                                                       const float* __restrict__ targ,
                                                       const float* __restrict__ Hbuf,
                                                       double* __restrict__ acc) {
    const int tid   = blockIdx.x * 256 + threadIdx.x;
    const int x     = tid & (WW - 1);
    const int bc    = tid >> 9;
    const int chunk = bc & (HH / YCHUNK - 1);   // 16 chunks
    const int b     = bc >> 4;
    const int y0    = chunk * YCHUNK;

    const size_t base = (size_t)b * HH * WW + x;
    const float* Hp = Hbuf   + base;
    const float* Tp = targ   + base;
    const float* Lp = logits + base;

    // warm-up: window sum for rows [y0-15, y0+15] (clipped low; high side <512)
    float vsum = 0.0f;
    {
        int lo = y0 - KRAD; if (lo < 0) lo = 0;
        const int hi = y0 + KRAD;
        for (int k = lo; k <= hi; ++k) vsum += Hp[(size_t)k * WW];
    }

    const float inv_ksq = 1.0f / (float)(KSZ * KSZ);
    float a_wbce = 0.0f, a_int = 0.0f, a_tot = 0.0f;

#pragma unroll 4
    for (int y = y0; y < y0 + YCHUNK; ++y) {
        const float s = vsum * inv_ksq;
        const float t = __builtin_nontemporal_load(Tp + (size_t)y * WW);
        const float L = __builtin_nontemporal_load(Lp + (size_t)y * WW);

        const float weit = 1.0f + 5.0f * fabsf(s - t);
        // shared exponential: e = exp(-|L|)
        const float e  = __expf(-fabsf(L));
        const float r  = __builtin_amdgcn_rcpf(1.0f + e);
        const float lg = __logf(1.0f + e);          // softplus(-|L|)
        const float sp  = fmaxf(L, 0.0f) + lg;      // softplus(L)
        const float bce = sp - t * L;
        const float p   = (L >= 0.0f) ? r : e * r;  // sigmoid(L)

        a_wbce += weit * bce;
        a_int  += p * t * weit;
        a_tot  += (p + t) * weit;

        // slide window: [y-15, y+15] -> [y-14, y+16]
        const int add = y + KRAD + 1;
        const int sub = y - KRAD;
        if (add <= HH - 1) vsum += Hp[(size_t)add * WW];
        if (sub >= 0)      vsum -= Hp[(size_t)sub * WW];
    }

    // wave reduce (64 lanes)
#pragma unroll
    for (int off = 32; off > 0; off >>= 1) {
        a_wbce += __shfl_down(a_wbce, off, 64);
        a_int  += __shfl_down(a_int,  off, 64);
        a_tot  += __shfl_down(a_tot,  off, 64);
    }

    __shared__ float red[3][4];
    const int wave = threadIdx.x >> 6;
    if ((threadIdx.x & 63) == 0) {
        red[0][wave] = a_wbce; red[1][wave] = a_int; red[2][wave] = a_tot;
    }
    __syncthreads();
    if (threadIdx.x == 0) {
        double w = 0.0, i2 = 0.0, t2 = 0.0;
        for (int k = 0; k < 4; ++k) { w += red[0][k]; i2 += red[1][k]; t2 += red[2][k]; }
        atomicAdd(&acc[0], w);
        atomicAdd(&acc[1], i2);
        atomicAdd(&acc[2], t2);
    }
}

// ---------------------------------------------------------------------------
// Pass 3: finalize the scalar.
// ---------------------------------------------------------------------------
__global__ void finalize_kernel(const double* __restrict__ acc, float* __restrict__ out) {
    if (threadIdx.x == 0 && blockIdx.x == 0) {
        const double wbce  = acc[0] / (double)NTOT;
        const double inter = acc[1];
        const double total = acc[2];
        const double union_ = total - inter;
        const double wiou  = 1.0 - (inter + 1.0) / (union_ + 1.0);
        out[0] = (float)(wbce + wiou);
    }
}

extern "C" void kernel_launch(void* const* d_in, const int* in_sizes, int n_in,
                              void* d_out, int out_size, void* d_ws, size_t ws_size,
                              hipStream_t stream) {
    const float* logits = (const float*)d_in[0];
    const float* targ   = (const float*)d_in[1];
    float* out          = (float*)d_out;

    double* acc  = (double*)d_ws;                       // 3 doubles @ offset 0
    float*  Hbuf = (float*)((char*)d_ws + 256);         // 64 MiB intermediate

    // Pass 1: horizontal box sums (also zeroes acc)
    hbox_kernel<<<BATCH * HH / 4, 256, 0, stream>>>(targ, Hbuf, acc);
    // Pass 2: vertical box + fused loss + reductions
    fused_kernel<<<(BATCH * (HH / YCHUNK) * WW) / 256, 256, 0, stream>>>(logits, targ, Hbuf, acc);
    // Pass 3: scalar finalize
    finalize_kernel<<<1, 64, 0, stream>>>(acc, out);
}

// Round 3
// 191.008 us; speedup vs baseline: 1.5153x; 1.3042x over previous
//
#include <hip/hip_runtime.h>
#include <math.h>

#define BATCH 64
#define HH 512
#define WW 512
#define KRAD 15
#define KSZ 31
#define NTOT ((size_t)BATCH * HH * WW)
#define YCHUNK 32
#define NBLK (BATCH * (HH / YCHUNK) * WW / 256)   // 2048 fused blocks

// ---------------------------------------------------------------------------
// Pass 1: horizontal 31-tap box sum (zero-padded) per row, via register
// prefix sums + wave shuffles. One wave (64 lanes) per 512-wide row,
// 8 columns per lane. 4 rows per 256-thread block. No LDS.
// (UNCHANGED from R2 so its true duration can be read when it surfaces.)
// ---------------------------------------------------------------------------
__global__ __launch_bounds__(256) void hbox_kernel(const float* __restrict__ t,
                                                   float* __restrict__ Hbuf) {
    const int g    = blockIdx.x * 4 + (threadIdx.x >> 6);  // global row (b*512+y)
    const int lane = threadIdx.x & 63;

    const float4* rp = (const float4*)(t + (size_t)g * WW);
    float4 a  = rp[2 * lane];
    float4 b4 = rp[2 * lane + 1];
    float v[8] = {a.x, a.y, a.z, a.w, b4.x, b4.y, b4.z, b4.w};

    // local inclusive prefix
    float T = 0.0f;
    float P[8];
#pragma unroll
    for (int j = 0; j < 8; ++j) { T += v[j]; P[j] = T; }

    // wave-inclusive scan of per-thread totals
    float incl = T;
#pragma unroll
    for (int d = 1; d < 64; d <<= 1) {
        float n = __shfl_up(incl, d, 64);
        if (lane >= d) incl += n;
    }
    const float excl = incl - T;
    const float tot  = __shfl(incl, 63, 64);  // full-row sum = P[511]

#pragma unroll
    for (int j = 0; j < 8; ++j) P[j] += excl;

    float o[8];
#pragma unroll
    for (int j = 0; j < 8; ++j) {
        const int q   = j + 15;              // 15..22 (compile-time)
        const int seg = lane + (q >> 3);     // lane+1 or lane+2
        float hi_sh = __shfl(P[q & 7], seg > 63 ? 63 : seg, 64);
        float hi    = (seg > 63) ? tot : hi_sh;
        float lo_sh = __shfl(P[j], lane >= 2 ? lane - 2 : 0, 64);
        float lo    = (lane >= 2) ? lo_sh : 0.0f;
        o[j] = hi - lo;
    }

    float4* dp = (float4*)(Hbuf + (size_t)g * WW);
    float4 s0 = {o[0], o[1], o[2], o[3]};
    float4 s1 = {o[4], o[5], o[6], o[7]};
    dp[2 * lane]     = s0;
    dp[2 * lane + 1] = s1;
}

// ---------------------------------------------------------------------------
// Pass 2: vertical 31-tap box (running sum) fused with loss math.
// Per-block partials -> plain stores (NO contended atomics).
// ---------------------------------------------------------------------------
__global__ __launch_bounds__(256, 8) void fused_kernel(const float* __restrict__ logits,
                                                       const float* __restrict__ targ,
                                                       const float* __restrict__ Hbuf,
                                                       float* __restrict__ pbuf) {
    const int tid   = blockIdx.x * 256 + threadIdx.x;
    const int x     = tid & (WW - 1);
    const int bc    = tid >> 9;
    const int chunk = bc & (HH / YCHUNK - 1);   // 16 chunks
    const int b     = bc >> 4;
    const int y0    = chunk * YCHUNK;

    const size_t base = (size_t)b * HH * WW + x;
    const float* Hp = Hbuf   + base;
    const float* Tp = targ   + base;
    const float* Lp = logits + base;

    // warm-up: window sum for rows [y0-15, y0+15] (clipped low; high side <512)
    float vsum = 0.0f;
    {
        int lo = y0 - KRAD; if (lo < 0) lo = 0;
        const int hi = y0 + KRAD;
        for (int k = lo; k <= hi; ++k) vsum += Hp[(size_t)k * WW];
    }

    const float inv_ksq = 1.0f / (float)(KSZ * KSZ);
    float a_wbce = 0.0f, a_int = 0.0f, a_tot = 0.0f;

#pragma unroll 4
    for (int y = y0; y < y0 + YCHUNK; ++y) {
        const float s = vsum * inv_ksq;
        const float t = __builtin_nontemporal_load(Tp + (size_t)y * WW);
        const float L = __builtin_nontemporal_load(Lp + (size_t)y * WW);

        const float weit = 1.0f + 5.0f * fabsf(s - t);
        const float e  = __expf(-fabsf(L));
        const float r  = __builtin_amdgcn_rcpf(1.0f + e);
        const float lg = __logf(1.0f + e);          // softplus(-|L|)
        const float sp  = fmaxf(L, 0.0f) + lg;      // softplus(L)
        const float bce = sp - t * L;
        const float p   = (L >= 0.0f) ? r : e * r;  // sigmoid(L)

        a_wbce += weit * bce;
        a_int  += p * t * weit;
        a_tot  += (p + t) * weit;

        const int add = y + KRAD + 1;
        const int sub = y - KRAD;
        if (add <= HH - 1) vsum += Hp[(size_t)add * WW];
        if (sub >= 0)      vsum -= Hp[(size_t)sub * WW];
    }

    // wave reduce (64 lanes)
#pragma unroll
    for (int off = 32; off > 0; off >>= 1) {
        a_wbce += __shfl_down(a_wbce, off, 64);
        a_int  += __shfl_down(a_int,  off, 64);
        a_tot  += __shfl_down(a_tot,  off, 64);
    }

    __shared__ float red[3][4];
    const int wave = threadIdx.x >> 6;
    if ((threadIdx.x & 63) == 0) {
        red[0][wave] = a_wbce; red[1][wave] = a_int; red[2][wave] = a_tot;
    }
    __syncthreads();
    if (threadIdx.x == 0) {
        float w = 0.0f, i2 = 0.0f, t2 = 0.0f;
        for (int k = 0; k < 4; ++k) { w += red[0][k]; i2 += red[1][k]; t2 += red[2][k]; }
        // plain stores: every block writes its own 3 slots (no contention)
        pbuf[blockIdx.x]            = w;
        pbuf[NBLK + blockIdx.x]     = i2;
        pbuf[2 * NBLK + blockIdx.x] = t2;
    }
}

// ---------------------------------------------------------------------------
// Pass 3: reduce 2048 partials per quantity (double accum) + finalize scalar.
// ---------------------------------------------------------------------------
__global__ __launch_bounds__(256) void finalize_kernel(const float* __restrict__ pbuf,
                                                       float* __restrict__ out) {
    const int tidx = threadIdx.x;
    double w = 0.0, i2 = 0.0, t2 = 0.0;
    for (int k = tidx; k < NBLK; k += 256) {
        w  += (double)pbuf[k];
        i2 += (double)pbuf[NBLK + k];
        t2 += (double)pbuf[2 * NBLK + k];
    }
#pragma unroll
    for (int off = 32; off > 0; off >>= 1) {
        w  += __shfl_down(w,  off, 64);
        i2 += __shfl_down(i2, off, 64);
        t2 += __shfl_down(t2, off, 64);
    }
    __shared__ double red[3][4];
    const int wave = tidx >> 6;
    if ((tidx & 63) == 0) { red[0][wave] = w; red[1][wave] = i2; red[2][wave] = t2; }
    __syncthreads();
    if (tidx == 0) {
        double ws = 0.0, is = 0.0, ts = 0.0;
        for (int k = 0; k < 4; ++k) { ws += red[0][k]; is += red[1][k]; ts += red[2][k]; }
        const double wbce   = ws / (double)NTOT;
        const double union_ = ts - is;
        const double wiou   = 1.0 - (is + 1.0) / (union_ + 1.0);
        out[0] = (float)(wbce + wiou);
    }
}

extern "C" void kernel_launch(void* const* d_in, const int* in_sizes, int n_in,
                              void* d_out, int out_size, void* d_ws, size_t ws_size,
                              hipStream_t stream) {
    const float* logits = (const float*)d_in[0];
    const float* targ   = (const float*)d_in[1];
    float* out          = (float*)d_out;

    float* pbuf = (float*)d_ws;                         // 3*NBLK floats (24 KB)
    float* Hbuf = (float*)((char*)d_ws + 65536);        // 64 MiB intermediate

    // Pass 1: horizontal box sums
    hbox_kernel<<<BATCH * HH / 4, 256, 0, stream>>>(targ, Hbuf);
    // Pass 2: vertical box + fused loss + per-block partials
    fused_kernel<<<NBLK, 256, 0, stream>>>(logits, targ, Hbuf, pbuf);
    // Pass 3: reduce partials + finalize
    finalize_kernel<<<1, 256, 0, stream>>>(pbuf, out);
}

// Round 4
// 153.266 us; speedup vs baseline: 1.8884x; 1.2462x over previous
//
#include <hip/hip_runtime.h>
#include <math.h>

#define BATCH 64
#define HH 512
#define WW 512
#define KRAD 15
#define KSZ 31
#define NTOT ((size_t)BATCH * HH * WW)
#define TILE_Y 32
#define NCHUNK (HH / TILE_Y)            // 16
#define NBLK (BATCH * NCHUNK)           // 1024 blocks
#define HROWS (TILE_Y + 2 * KRAD)       // 62 LDS rows

typedef _Float16 h8 __attribute__((ext_vector_type(8)));

// ---------------------------------------------------------------------------
// One kernel: per-block H-pass (wave shuffle-scan -> fp16 LDS strip) + V-pass
// running sum + loss math + block reduction. No Hbuf in HBM, no hbox kernel.
// Block = 512 threads (8 waves), LDS = 62*512 fp16 = 62 KB -> 2 blocks/CU.
// ---------------------------------------------------------------------------
__global__ __launch_bounds__(512, 4) void mega_kernel(const float* __restrict__ logits,
                                                      const float* __restrict__ targ,
                                                      float* __restrict__ pbuf) {
    __shared__ _Float16 Hlds[HROWS * WW];

    const int b     = blockIdx.x >> 4;          // batch
    const int chunk = blockIdx.x & (NCHUNK - 1);
    const int y0    = chunk * TILE_Y;

    const int wave = threadIdx.x >> 6;
    const int lane = threadIdx.x & 63;

    // ---- Stage 1: compute H rows [y0-15, y0+46] into LDS (fp16) ----
    // Each wave scans rows r = 8*i + wave (verified shuffle-scan from hbox).
#pragma unroll
    for (int i = 0; i < 8; ++i) {
        const int r = i * 8 + wave;             // 0..63
        if (r >= HROWS) continue;               // wave-uniform
        const int y_abs = y0 - KRAD + r;

        h8 hv = {};
        if (y_abs >= 0 && y_abs < HH) {
            const float4* rp = (const float4*)(targ + ((size_t)b * HH + y_abs) * WW);
            float4 a  = rp[2 * lane];
            float4 b4 = rp[2 * lane + 1];
            float v[8] = {a.x, a.y, a.z, a.w, b4.x, b4.y, b4.z, b4.w};

            float T = 0.0f;
            float P[8];
#pragma unroll
            for (int j = 0; j < 8; ++j) { T += v[j]; P[j] = T; }

            float incl = T;
#pragma unroll
            for (int d = 1; d < 64; d <<= 1) {
                float n = __shfl_up(incl, d, 64);
                if (lane >= d) incl += n;
            }
            const float excl = incl - T;
            const float tot  = __shfl(incl, 63, 64);
#pragma unroll
            for (int j = 0; j < 8; ++j) P[j] += excl;

#pragma unroll
            for (int j = 0; j < 8; ++j) {
                const int q   = j + 15;             // 15..22 (compile-time)
                const int seg = lane + (q >> 3);
                float hi_sh = __shfl(P[q & 7], seg > 63 ? 63 : seg, 64);
                float hi    = (seg > 63) ? tot : hi_sh;
                float lo_sh = __shfl(P[j], lane >= 2 ? lane - 2 : 0, 64);
                float lo    = (lane >= 2) ? lo_sh : 0.0f;
                hv[j] = (_Float16)(hi - lo);
            }
        }
        *(h8*)&Hlds[r * WW + lane * 8] = hv;    // 16B aligned, contiguous
    }
    __syncthreads();

    // ---- Stage 2: per-column vertical running sum + loss math ----
    const int x = threadIdx.x;                  // 512 threads <-> 512 columns
    const size_t base = ((size_t)b * HH + y0) * WW + x;
    const float* Tp = targ   + base;
    const float* Lp = logits + base;

    float vsum = 0.0f;
#pragma unroll
    for (int r = 0; r < KSZ; ++r) vsum += (float)Hlds[r * WW + x];

    const float inv_ksq = 1.0f / (float)(KSZ * KSZ);
    float a_wbce = 0.0f, a_int = 0.0f, a_tot = 0.0f;

#pragma unroll 4
    for (int y = 0; y < TILE_Y; ++y) {
        const float s = vsum * inv_ksq;
        const float t = Tp[(size_t)y * WW];
        const float L = __builtin_nontemporal_load(Lp + (size_t)y * WW);

        const float weit = 1.0f + 5.0f * fabsf(s - t);
        const float e  = __expf(-fabsf(L));
        const float r  = __builtin_amdgcn_rcpf(1.0f + e);
        const float lg = __logf(1.0f + e);          // softplus(-|L|)
        const float sp  = fmaxf(L, 0.0f) + lg;      // softplus(L)
        const float bce = sp - t * L;
        const float p   = (L >= 0.0f) ? r : e * r;  // sigmoid(L)

        a_wbce += weit * bce;
        a_int  += p * t * weit;
        a_tot  += (p + t) * weit;

        if (y < TILE_Y - 1)
            vsum += (float)Hlds[(y + KSZ) * WW + x] - (float)Hlds[y * WW + x];
    }

    // ---- Block reduction: wave shuffle + LDS + plain per-block stores ----
#pragma unroll
    for (int off = 32; off > 0; off >>= 1) {
        a_wbce += __shfl_down(a_wbce, off, 64);
        a_int  += __shfl_down(a_int,  off, 64);
        a_tot  += __shfl_down(a_tot,  off, 64);
    }

    __shared__ float red[3][8];
    if (lane == 0) {
        red[0][wave] = a_wbce; red[1][wave] = a_int; red[2][wave] = a_tot;
    }
    __syncthreads();
    if (threadIdx.x == 0) {
        float w = 0.0f, i2 = 0.0f, t2 = 0.0f;
#pragma unroll
        for (int k = 0; k < 8; ++k) { w += red[0][k]; i2 += red[1][k]; t2 += red[2][k]; }
        pbuf[blockIdx.x]            = w;
        pbuf[NBLK + blockIdx.x]     = i2;
        pbuf[2 * NBLK + blockIdx.x] = t2;
    }
}

// ---------------------------------------------------------------------------
// Finalize: reduce 1024 partials per quantity (double accum) + scalar.
// ---------------------------------------------------------------------------
__global__ __launch_bounds__(256) void finalize_kernel(const float* __restrict__ pbuf,
                                                       float* __restrict__ out) {
    const int tidx = threadIdx.x;
    double w = 0.0, i2 = 0.0, t2 = 0.0;
    for (int k = tidx; k < NBLK; k += 256) {
        w  += (double)pbuf[k];
        i2 += (double)pbuf[NBLK + k];
        t2 += (double)pbuf[2 * NBLK + k];
    }
#pragma unroll
    for (int off = 32; off > 0; off >>= 1) {
        w  += __shfl_down(w,  off, 64);
        i2 += __shfl_down(i2, off, 64);
        t2 += __shfl_down(t2, off, 64);
    }
    __shared__ double red[3][4];
    const int wave = tidx >> 6;
    if ((tidx & 63) == 0) { red[0][wave] = w; red[1][wave] = i2; red[2][wave] = t2; }
    __syncthreads();
    if (tidx == 0) {
        double ws = 0.0, is = 0.0, ts = 0.0;
        for (int k = 0; k < 4; ++k) { ws += red[0][k]; is += red[1][k]; ts += red[2][k]; }
        const double wbce   = ws / (double)NTOT;
        const double union_ = ts - is;
        const double wiou   = 1.0 - (is + 1.0) / (union_ + 1.0);
        out[0] = (float)(wbce + wiou);
    }
}

extern "C" void kernel_launch(void* const* d_in, const int* in_sizes, int n_in,
                              void* d_out, int out_size, void* d_ws, size_t ws_size,
                              hipStream_t stream) {
    const float* logits = (const float*)d_in[0];
    const float* targ   = (const float*)d_in[1];
    float* out          = (float*)d_out;
    float* pbuf         = (float*)d_ws;     // 3*NBLK floats (12 KB)

    mega_kernel<<<NBLK, 512, 0, stream>>>(logits, targ, pbuf);
    finalize_kernel<<<1, 256, 0, stream>>>(pbuf, out);
}